// Round 9
// baseline (96.621 us; speedup 1.0000x reference)
//
#include <hip/hip_runtime.h>
#include <cstddef>

typedef float f4 __attribute__((ext_vector_type(4)));
typedef __bf16 bf16x8 __attribute__((ext_vector_type(8)));
typedef float f32x16 __attribute__((ext_vector_type(16)));

constexpr int D_ = 128;     // d_model
constexpr int LAYERS = 4;
constexpr int BM = 128;     // tokens per block = 4 waves x 32 tokens
constexpr int NT = 256;

// prep: W^T in MFMA A-frag order with the cur-half k-dimension PERMUTED by sigma
// so that layer d's D-output registers are layer d+1's B-fragments in-place.
// wt2[((d*4 + c)*16 + f)*512 + lane*8 + j] = A_phys[d][n = c*32 + (lane&31)]
//                                                  [k = f*16 + (lane>>5)*8 + j]
// A_phys[d][n][k] = k<128 ? W[d][g(k)][n]  (cur rows, permuted)
//                         : W[d][k][n]     (x rows, natural)
// g(k): j=k&7, h=(k>>3)&1, f=(k>>4)&7 -> (f>>1)*32 + (2*(f&1)+(j>>2))*8 + 4*h + (j&3)
// Layer 0 folds concat([x,x]): W0[0:128]+W0[128:256] into k in [128,256), zeros below.
__global__ void prep(const float* __restrict__ Wl, __bf16* __restrict__ wt2) {
    int idx = blockIdx.x * 256 + threadIdx.x;        // 4*4*16*64*8 = 131072
    int j = idx & 7, lane = (idx >> 3) & 63, f = (idx >> 9) & 15,
        c = (idx >> 13) & 3, d = idx >> 15;
    int n = c * 32 + (lane & 31);
    int k = f * 16 + (lane >> 5) * 8 + j;            // physical k
    float v;
    if (d == 0) {
        v = (k < 128) ? 0.f
                      : (Wl[(size_t)(k - 128) * D_ + n] + Wl[(size_t)k * D_ + n]);
    } else {
        int kl;
        if (k < 128) {
            int jj = k & 7, hh = (k >> 3) & 1, ff = (k >> 4) & 7;
            kl = (ff >> 1) * 32 + ((ff & 1) * 2 + (jj >> 2)) * 8 + hh * 4 + (jj & 3);
        } else {
            kl = k;
        }
        v = Wl[(size_t)d * 2 * D_ * D_ + (size_t)kl * D_ + n];
    }
    wt2[idx] = (__bf16)v;
}

__global__ __launch_bounds__(NT, 3)   // target <=170 VGPR -> 3 waves/SIMD
void moe_fwd(const float* __restrict__ x, const float* __restrict__ Wr,
             const __bf16* __restrict__ wt2, const float* __restrict__ bl,
             const float* __restrict__ We, const float* __restrict__ be,
             float* __restrict__ out)
{
    __shared__ float CSM[BM][4];       // per-token 0/1 gate coefs (only LDS in kernel)

    const int t    = threadIdx.x;
    const int m0   = blockIdx.x * BM;
    const int lane = t & 63, w = t >> 6;
    const int lo5  = lane & 31, hi = lane >> 5;
    const int tok  = w * 32 + lo5;           // this wave's token (B/D column)
    const int grp  = t >> 4, il = t & 15;    // 16 lanes per token row (gate phase)

    // ---- x B-frags -> registers (issued first; latency hides under gate compute) ----
    // xb[fi][j] = bf16( x[tok][ fi*16 + hi*8 + j ] )   (per row: 64B contiguous/lane-pair)
    bf16x8 xb[8];
    #pragma unroll
    for (int fi = 0; fi < 8; ++fi) {
        const f4* gx = (const f4*)(x + (size_t)(m0 + tok) * D_ + fi * 16 + hi * 8);
        f4 a = gx[0], b = gx[1];
        xb[fi][0] = (__bf16)a[0]; xb[fi][1] = (__bf16)a[1];
        xb[fi][2] = (__bf16)a[2]; xb[fi][3] = (__bf16)a[3];
        xb[fi][4] = (__bf16)b[0]; xb[fi][5] = (__bf16)b[1];
        xb[fi][6] = (__bf16)b[2]; xb[fi][7] = (__bf16)b[3];
    }

    // ---- gates in f64 (same 16-lane-group structure/order as passing R4-R8) ----
    {
        f4 wrv[8];
        #pragma unroll
        for (int j = 0; j < 8; ++j)
            wrv[j] = *(const f4*)(Wr + (il * 8 + j) * 4);
        #pragma unroll
        for (int i = 0; i < 8; ++i) {
            const int row = i * 16 + grp;
            const f4* gx = (const f4*)(x + (size_t)(m0 + row) * D_ + il * 8);
            f4 lo = gx[0], hp = gx[1];
            double a0 = 0, a1 = 0, a2 = 0, a3 = 0;
            #pragma unroll
            for (int j = 0; j < 4; ++j) {
                double xv = (double)lo[j];
                a0 += xv * (double)wrv[j][0]; a1 += xv * (double)wrv[j][1];
                a2 += xv * (double)wrv[j][2]; a3 += xv * (double)wrv[j][3];
            }
            #pragma unroll
            for (int j = 0; j < 4; ++j) {
                double xv = (double)hp[j];
                a0 += xv * (double)wrv[4 + j][0]; a1 += xv * (double)wrv[4 + j][1];
                a2 += xv * (double)wrv[4 + j][2]; a3 += xv * (double)wrv[4 + j][3];
            }
            #pragma unroll
            for (int s = 1; s < 16; s <<= 1) {
                a0 += __shfl_xor(a0, s, 16);
                a1 += __shfl_xor(a1, s, 16);
                a2 += __shfl_xor(a2, s, 16);
                a3 += __shfl_xor(a3, s, 16);
            }
            if (il == 0) {
                f4 c;
                c[0] = a0 > 0.0 ? 1.f : 0.f; c[1] = a1 > 0.0 ? 1.f : 0.f;
                c[2] = a2 > 0.0 ? 1.f : 0.f; c[3] = a3 > 0.0 ? 1.f : 0.f;
                *(f4*)(&CSM[row][0]) = c;
            }
        }
    }
    __syncthreads();                         // the ONLY barrier in this kernel
    f4 cfv = *(const f4*)(&CSM[tok][0]);     // this token's 4 gate coefs

    float outc = 0.f;
    bf16x8 pb[8];                            // cur B-frags (written at end of each layer)

    #pragma unroll
    for (int d = 0; d < LAYERS; ++d) {
        f32x16 acc[4];
        #pragma unroll
        for (int c = 0; c < 4; ++c)
            #pragma unroll
            for (int j = 0; j < 16; ++j) acc[c][j] = 0.f;

        const __bf16* wb = wt2 + (size_t)(d * 4 * 16) * 512 + (size_t)lane * 8;
        #pragma unroll
        for (int c = 0; c < 4; ++c) {        // n-chunk: n in [c*32, c*32+32)
            bf16x8 wf[16];
            #pragma unroll
            for (int f = (d == 0 ? 8 : 0); f < 16; ++f)
                wf[f] = *(const bf16x8*)(wb + (size_t)(c * 16 + f) * 512);
            #pragma unroll
            for (int f = (d == 0 ? 8 : 0); f < 16; ++f)
                acc[c] = __builtin_amdgcn_mfma_f32_32x32x16_bf16(
                             wf[f], (f < 8) ? pb[f] : xb[f - 8], acc[c], 0, 0, 0);
        }

        // ---- epilogue: bias+relu (fp32), estimator dot, cur -> pb (registers) ----
        // value (c, r=rg*4+q): n = c*32 + rg*8 + hi*4 + q  ->  pb[c*2+(rg>>1)][(rg&1)*4+q]
        float p = 0.f;
        #pragma unroll
        for (int c = 0; c < 4; ++c) {
            #pragma unroll
            for (int rg = 0; rg < 4; ++rg) {
                int nb = c * 32 + rg * 8 + hi * 4;
                f4 bv = *(const f4*)(bl + d * D_ + nb);
                f4 ev = *(const f4*)(We + d * D_ + nb);
                float c0 = fmaxf(acc[c][rg * 4 + 0] + bv[0], 0.f);
                float c1 = fmaxf(acc[c][rg * 4 + 1] + bv[1], 0.f);
                float c2 = fmaxf(acc[c][rg * 4 + 2] + bv[2], 0.f);
                float c3 = fmaxf(acc[c][rg * 4 + 3] + bv[3], 0.f);
                p += c0 * ev[0] + c1 * ev[1] + c2 * ev[2] + c3 * ev[3];
                if (d < LAYERS - 1) {
                    const int f = c * 2 + (rg >> 1), jb = (rg & 1) * 4;
                    pb[f][jb + 0] = (__bf16)c0; pb[f][jb + 1] = (__bf16)c1;
                    pb[f][jb + 2] = (__bf16)c2; pb[f][jb + 3] = (__bf16)c3;
                }
            }
        }
        p += __shfl_xor(p, 32, 64);          // combine hi-halves: full pred[token]
        if (lane < 32) outc += cfv[d] * (p + be[d]);
    }

    if (lane < 32) out[m0 + tok] = outc;
}

extern "C" void kernel_launch(void* const* d_in, const int* in_sizes, int n_in,
                              void* d_out, int out_size, void* d_ws, size_t ws_size,
                              hipStream_t stream) {
    const float* x  = (const float*)d_in[0];
    const float* Wr = (const float*)d_in[1];
    const float* Wl = (const float*)d_in[2];
    const float* bl = (const float*)d_in[3];
    const float* We = (const float*)d_in[4];
    const float* be = (const float*)d_in[5];
    float* out = (float*)d_out;
    __bf16* wt2 = (__bf16*)d_ws;                // 256 KB scratch for permuted W^T frags
    const int B = in_sizes[0] / D_;             // 131072

    prep<<<dim3(512), dim3(256), 0, stream>>>(Wl, wt2);
    moe_fwd<<<dim3(B / BM), dim3(NT), 0, stream>>>(x, Wr, wt2, bl, We, be, out);
}

// Round 10
// 87.960 us; speedup vs baseline: 1.0985x; 1.0985x over previous
//
#include <hip/hip_runtime.h>
#include <cstddef>

typedef float f4 __attribute__((ext_vector_type(4)));
typedef __bf16 bf16x8 __attribute__((ext_vector_type(8)));
typedef __bf16 bf16x4 __attribute__((ext_vector_type(4)));
typedef float f32x16 __attribute__((ext_vector_type(16)));

constexpr int D_ = 128;     // d_model
constexpr int LAYERS = 4;
constexpr int BM = 64;      // tokens per block (small tile -> 4 blocks/CU)
constexpr int NT = 512;     // 8 waves: 4 nf (32-n frags) x 2 tw (32-token groups)
constexpr int ROWB = 512;   // A-tile row stride bytes (256 bf16)

// XOR swizzle (T2/G4): spreads 16B slots across banks for stride-512B rows.
__device__ __forceinline__ int swz(int row, int woff) {
    return row * ROWB + (woff ^ ((row & 15) << 4));
}

// prep: W^T in MFMA A-fragment order (R5 version, no permutation).
// wt2[((d*4 + nf)*16 + kc)*512 + lane*8 + j] = W^T[d][n = nf*32 + (lane&31)]
//                                                  [k = kc*16 + (lane>>5)*8 + j]
// Layer 0 folds concat([x,x]): top+bot summed into k in [128,256), zeros below.
__global__ void prep(const float* __restrict__ Wl, __bf16* __restrict__ wt2) {
    int idx = blockIdx.x * 256 + threadIdx.x;        // 4*4*16*512 = 131072
    int j = idx & 7, lane = (idx >> 3) & 63, kc = (idx >> 9) & 15,
        nf = (idx >> 13) & 3, d = idx >> 15;
    int n  = nf * 32 + (lane & 31);
    int ks = kc * 16 + (lane >> 5) * 8 + j;
    float v;
    if (d == 0)
        v = (ks < 128) ? 0.f
                       : (Wl[(size_t)(ks - 128) * D_ + n] + Wl[(size_t)ks * D_ + n]);
    else
        v = Wl[(size_t)d * 2 * D_ * D_ + (size_t)ks * D_ + n];
    wt2[idx] = (__bf16)v;
}

__global__ __launch_bounds__(NT, 8)   // 8 waves/EU: force VGPR<=64, 100% occupancy
void moe_fwd(const float* __restrict__ x, const float* __restrict__ Wr,
             const __bf16* __restrict__ wt2, const float* __restrict__ bl,
             const float* __restrict__ We, const float* __restrict__ be,
             float* __restrict__ out)
{
    __shared__ char Ab[BM * ROWB];     // 32 KB: [token][256 k] bf16 swizzled (k<128 cur, k>=128 x)
    __shared__ float PR[4][BM];        // per-nf estimator partials
    __shared__ float CSM[BM][4];       // per-token 0/1 gate coefs

    const int t    = threadIdx.x;
    const int m0   = blockIdx.x * BM;
    const int lane = t & 63, w = t >> 6;
    const int nf   = w >> 1;            // 0..3: n in [nf*32, nf*32+32)
    const int tw   = w & 1;             // 0..1: 32-token group
    const int lo5  = lane & 31, hi = lane >> 5;
    const int hi16 = hi * 16;
    const int tok0 = tw * 32 + lo5;     // this wave's token (B/D column)
    const int grp  = t >> 4, il = t & 15;   // 16 lanes per token row (32 groups)

    // ---- fused: stage x -> Ab (bf16, swizzled) + f64 gates from same registers ----
    // iteration i: this thread handles token row 32i + grp, cols il*8 .. il*8+7.
    // Wr rows reloaded per use (2 KB, L1-hot) to keep peak VGPR under the 64 cap.
    #pragma unroll
    for (int i = 0; i < 2; ++i) {
        const int row = i * 32 + grp;
        const f4* gx = (const f4*)(x + (size_t)(m0 + row) * D_ + il * 8);
        f4 lo = gx[0], hp = gx[1];
        bf16x8 v;
        v[0] = (__bf16)lo[0]; v[1] = (__bf16)lo[1]; v[2] = (__bf16)lo[2]; v[3] = (__bf16)lo[3];
        v[4] = (__bf16)hp[0]; v[5] = (__bf16)hp[1]; v[6] = (__bf16)hp[2]; v[7] = (__bf16)hp[3];
        *(bf16x8*)(Ab + swz(row, 256 + il * 16)) = v;

        double a0 = 0, a1 = 0, a2 = 0, a3 = 0;
        #pragma unroll
        for (int j = 0; j < 4; ++j) {
            f4 wv = *(const f4*)(Wr + (il * 8 + j) * 4);
            double xv = (double)lo[j];
            a0 += xv * (double)wv[0]; a1 += xv * (double)wv[1];
            a2 += xv * (double)wv[2]; a3 += xv * (double)wv[3];
        }
        #pragma unroll
        for (int j = 0; j < 4; ++j) {
            f4 wv = *(const f4*)(Wr + (il * 8 + 4 + j) * 4);
            double xv = (double)hp[j];
            a0 += xv * (double)wv[0]; a1 += xv * (double)wv[1];
            a2 += xv * (double)wv[2]; a3 += xv * (double)wv[3];
        }
        #pragma unroll
        for (int s = 1; s < 16; s <<= 1) {   // 16-lane f64 tree reduce
            a0 += __shfl_xor(a0, s, 16);
            a1 += __shfl_xor(a1, s, 16);
            a2 += __shfl_xor(a2, s, 16);
            a3 += __shfl_xor(a3, s, 16);
        }
        if (il == 0) {
            f4 c;
            c[0] = a0 > 0.0 ? 1.f : 0.f; c[1] = a1 > 0.0 ? 1.f : 0.f;
            c[2] = a2 > 0.0 ? 1.f : 0.f; c[3] = a3 > 0.0 ? 1.f : 0.f;
            *(f4*)(&CSM[row][0]) = c;
        }
    }

    float outc = 0.f;
    __syncthreads();

    #pragma unroll
    for (int d = 0; d < LAYERS; ++d) {
        f32x16 acc;
        #pragma unroll
        for (int j = 0; j < 16; ++j) acc[j] = 0.f;

        const __bf16* wb = wt2 + ((size_t)(d * 4 + nf) * 16) * 512 + lane * 8;
        #pragma unroll
        for (int ks = 0; ks < 16; ++ks) {
            if (ks < (d == 0 ? 8 : 0)) continue;    // compile-time (d unrolled)
            bf16x8 wf = *(const bf16x8*)(wb + (size_t)ks * 512);
            bf16x8 b0 = *(const bf16x8*)(Ab + swz(tok0, ks * 32 + hi16));
            acc = __builtin_amdgcn_mfma_f32_32x32x16_bf16(wf, b0, acc, 0, 0, 0);
        }
        __syncthreads();   // all Ab reads of this layer done before cur overwrite

        // ---- epilogue: bias+relu (fp32), estimator dot, cur -> Ab (bf16) ----
        // D[n][token]: token = lane&31, n = (reg&3) + 8*(reg>>2) + 4*hi (+32*nf)
        float p = 0.f;
        #pragma unroll
        for (int rg = 0; rg < 4; ++rg) {
            int nb = nf * 32 + rg * 8 + hi * 4;
            f4 bv = *(const f4*)(bl + d * D_ + nb);
            f4 ev = *(const f4*)(We + d * D_ + nb);
            float c0 = fmaxf(acc[rg * 4 + 0] + bv[0], 0.f);
            float c1 = fmaxf(acc[rg * 4 + 1] + bv[1], 0.f);
            float c2 = fmaxf(acc[rg * 4 + 2] + bv[2], 0.f);
            float c3 = fmaxf(acc[rg * 4 + 3] + bv[3], 0.f);
            p += c0 * ev[0] + c1 * ev[1] + c2 * ev[2] + c3 * ev[3];
            if (d < LAYERS - 1) {
                bf16x4 cc;
                cc[0] = (__bf16)c0; cc[1] = (__bf16)c1;
                cc[2] = (__bf16)c2; cc[3] = (__bf16)c3;
                *(bf16x4*)(Ab + swz(tok0, nb * 2)) = cc;
            }
        }
        p += __shfl_xor(p, 32, 64);          // combine hi halves (same token)
        if (lane < 32) PR[nf][tok0] = p;
        __syncthreads();   // cur + PR (and, for d=0, CSM) visible

        if (t < BM)
            outc += CSM[t][d] * (PR[0][t] + PR[1][t] + PR[2][t] + PR[3][t] + be[d]);
    }

    if (t < BM) out[m0 + t] = outc;
}

extern "C" void kernel_launch(void* const* d_in, const int* in_sizes, int n_in,
                              void* d_out, int out_size, void* d_ws, size_t ws_size,
                              hipStream_t stream) {
    const float* x  = (const float*)d_in[0];
    const float* Wr = (const float*)d_in[1];
    const float* Wl = (const float*)d_in[2];
    const float* bl = (const float*)d_in[3];
    const float* We = (const float*)d_in[4];
    const float* be = (const float*)d_in[5];
    float* out = (float*)d_out;
    __bf16* wt2 = (__bf16*)d_ws;                // 256 KB scratch for W^T frags
    const int B = in_sizes[0] / D_;             // 131072

    prep<<<dim3(512), dim3(256), 0, stream>>>(Wl, wt2);
    moe_fwd<<<dim3(B / BM), dim3(NT), 0, stream>>>(x, Wr, wt2, bl, We, be, out);
}